// Round 2
// baseline (321.427 us; speedup 1.0000x reference)
//
#include <hip/hip_runtime.h>
#include <math.h>

#define BB 8
#define CH 128
#define HH 64
#define WWID 64
#define HIN 62
#define WIN 62
#define SPIN (HIN*WIN)      // 3844
#define HP 66
#define WP 66
#define GG 4
#define GCH 32
#define PPT 9
#define NPIX (BB*HH*WWID)   // 32768

// ---------------- T0: transpose conv_w [Cout][Cin] -> w1t[k][cout] ----------
__global__ __launch_bounds__(256) void t0_wtrans(const float* __restrict__ conv_w,
                                                 float* __restrict__ w1t) {
    int idx = blockIdx.x * 256 + threadIdx.x;      // 0..16383
    int cout = idx >> 7, k = idx & 127;
    w1t[k * CH + cout] = conv_w[cout * CH + k];
}

// ---------------- T1: transpose x NCHW [B][128][3844] -> xt [B][3844][128] --
__global__ __launch_bounds__(256) void t1_xtrans(const float* __restrict__ x,
                                                 float* __restrict__ xt) {
    __shared__ float tile[32][33];
    int b = blockIdx.z;
    int c0 = blockIdx.y * 32;
    int s0 = blockIdx.x * 32;
    int tx = threadIdx.x & 31, ty = threadIdx.x >> 5;   // 32 x 8
    const float* xb = x + (size_t)b * CH * SPIN;
    #pragma unroll
    for (int i = 0; i < 32; i += 8) {
        int c = c0 + ty + i, s = s0 + tx;
        tile[ty + i][tx] = (s < SPIN) ? xb[(size_t)c * SPIN + s] : 0.f;
    }
    __syncthreads();
    float* xtb = xt + (size_t)b * SPIN * CH;
    #pragma unroll
    for (int i = 0; i < 32; i += 8) {
        int s = s0 + ty + i, c = c0 + tx;
        if (s < SPIN) xtb[(size_t)s * CH + c] = tile[tx][ty + i];
    }
}

// ---------------- K1: 1x1 conv (pad=1) -> y NHWC [B][64][64][128] -----------
__global__ __launch_bounds__(256) void k1_conv1x1(const float* __restrict__ xt,
                                                  const float* __restrict__ w1t,
                                                  const float* __restrict__ conv_b,
                                                  float* __restrict__ y) {
    __shared__ float xs[32 * CH];
    int pix0 = blockIdx.x * 32;
    int t = threadIdx.x;
    float4* xs4 = (float4*)xs;
    for (int q = t; q < 1024; q += 256) {
        int p = q >> 5, c4 = q & 31;
        int pix = pix0 + p;
        int w = pix & 63, h = (pix >> 6) & 63, b = pix >> 12;
        float4 v = make_float4(0.f, 0.f, 0.f, 0.f);
        if (h >= 1 && h <= 62 && w >= 1 && w <= 62) {
            const float4* src = (const float4*)(xt + (size_t)((b * HIN + (h - 1)) * WIN + (w - 1)) * CH);
            v = src[c4];
        }
        xs4[q] = v;
    }
    __syncthreads();
    int c = t & 127, half = t >> 7;
    int pbase = half * 16;
    float acc[16];
    float bv = conv_b[c];
    #pragma unroll
    for (int p = 0; p < 16; p++) acc[p] = bv;
    for (int k = 0; k < CH; k += 4) {
        float w0 = w1t[(k + 0) * CH + c];
        float w1 = w1t[(k + 1) * CH + c];
        float w2 = w1t[(k + 2) * CH + c];
        float w3 = w1t[(k + 3) * CH + c];
        #pragma unroll
        for (int p = 0; p < 16; p++) {
            float4 xv = *(const float4*)&xs[(pbase + p) * CH + k];
            acc[p] += xv.x * w0 + xv.y * w1 + xv.z * w2 + xv.w * w3;
        }
    }
    #pragma unroll
    for (int p = 0; p < 16; p++) {
        int pix = pix0 + pbase + p;
        y[(size_t)pix * CH + c] = acc[p];
    }
}

// ---------------- K2: in_proj -> xpad interior [B][66][66][128] -------------
__global__ __launch_bounds__(256) void k2_inproj(const float* __restrict__ y,
                                                 const float* __restrict__ Wm,
                                                 const float* __restrict__ bias,
                                                 float* __restrict__ xpad) {
    __shared__ float xs[32 * CH];
    int pix0 = blockIdx.x * 32;
    int t = threadIdx.x;
    const float4* src = (const float4*)(y + (size_t)pix0 * CH);
    float4* xs4 = (float4*)xs;
    for (int q = t; q < 1024; q += 256) xs4[q] = src[q];
    __syncthreads();
    int c = t & 127, half = t >> 7;
    int pbase = half * 16;
    float acc[16];
    float bv = bias[c];
    #pragma unroll
    for (int p = 0; p < 16; p++) acc[p] = bv;
    for (int k = 0; k < CH; k += 4) {
        float w0 = Wm[(k + 0) * CH + c];
        float w1 = Wm[(k + 1) * CH + c];
        float w2 = Wm[(k + 2) * CH + c];
        float w3 = Wm[(k + 3) * CH + c];
        #pragma unroll
        for (int p = 0; p < 16; p++) {
            float4 xv = *(const float4*)&xs[(pbase + p) * CH + k];
            acc[p] += xv.x * w0 + xv.y * w1 + xv.z * w2 + xv.w * w3;
        }
    }
    #pragma unroll
    for (int p = 0; p < 16; p++) {
        int pix = pix0 + pbase + p;
        int w = pix & 63, h = (pix >> 6) & 63, b = pix >> 12;
        xpad[(size_t)(((b * HP) + h + 1) * WP + (w + 1)) * CH + c] = acc[p];
    }
}

// ---------------- K3: depthwise 3x3 + LayerNorm + GELU -> d -----------------
__global__ __launch_bounds__(256) void k3_dwln(const float* __restrict__ y,
                                               const float* __restrict__ dw_w,
                                               const float* __restrict__ dw_b,
                                               const float* __restrict__ ln_g,
                                               const float* __restrict__ ln_b,
                                               float* __restrict__ d) {
    int t = threadIdx.x;
    int pl = t >> 7;                 // pixel-in-block 0/1
    int pix = blockIdx.x * 2 + pl;
    int c = t & 127;
    int w = pix & 63, h = (pix >> 6) & 63, b = pix >> 12;
    float acc = dw_b[c];
    #pragma unroll
    for (int ky = 0; ky < 3; ky++) {
        int hh = h + ky - 1;
        if (hh < 0 || hh > 63) continue;
        #pragma unroll
        for (int kx = 0; kx < 3; kx++) {
            int ww = w + kx - 1;
            if (ww < 0 || ww > 63) continue;
            acc += y[(size_t)((b * HH + hh) * WWID + ww) * CH + c] * dw_w[c * 9 + ky * 3 + kx];
        }
    }
    float s = acc, ss = acc * acc;
    #pragma unroll
    for (int off = 1; off < 64; off <<= 1) {
        s  += __shfl_xor(s, off);
        ss += __shfl_xor(ss, off);
    }
    __shared__ float red[8];
    int wave = t >> 6;               // waves 0,1 -> pixel 0; waves 2,3 -> pixel 1
    if ((t & 63) == 0) { red[wave * 2] = s; red[wave * 2 + 1] = ss; }
    __syncthreads();
    // pixel pl owns waves 2*pl and 2*pl+1 -> red slots [4*pl .. 4*pl+3]
    float S  = red[pl * 4 + 0] + red[pl * 4 + 2];
    float SS = red[pl * 4 + 1] + red[pl * 4 + 3];
    float mu = S * (1.f / 128.f);
    float var = SS * (1.f / 128.f) - mu * mu;
    float xln = (acc - mu) * rsqrtf(var + 1e-5f) * ln_g[c] + ln_b[c];
    float gel = 0.5f * xln * (1.f + erff(xln * 0.70710678118654752f));
    d[(size_t)pix * CH + c] = gel;
}

// ---------------- K4: offset(72) + mask-logits(36) GEMM -> om [pix][108] ----
__global__ __launch_bounds__(256) void k4_offmask(const float* __restrict__ din,
                                                  const float* __restrict__ off_w,
                                                  const float* __restrict__ off_b,
                                                  const float* __restrict__ mask_w,
                                                  const float* __restrict__ mask_b,
                                                  float* __restrict__ om) {
    __shared__ float xs[32 * CH];
    int pix0 = blockIdx.x * 32;
    int t = threadIdx.x;
    const float4* src = (const float4*)(din + (size_t)pix0 * CH);
    float4* xs4 = (float4*)xs;
    for (int q = t; q < 1024; q += 256) xs4[q] = src[q];
    __syncthreads();
    int c = t & 127, half = t >> 7;
    int pbase = half * 16;
    bool act = (c < 108);
    float acc[16];
    float bv = 0.f;
    if (c < 72) bv = off_b[c];
    else if (c < 108) bv = mask_b[c - 72];
    #pragma unroll
    for (int p = 0; p < 16; p++) acc[p] = bv;
    for (int k = 0; k < CH; k += 4) {
        float w0 = 0.f, w1 = 0.f, w2 = 0.f, w3 = 0.f;
        if (c < 72) {
            w0 = off_w[(k + 0) * 72 + c]; w1 = off_w[(k + 1) * 72 + c];
            w2 = off_w[(k + 2) * 72 + c]; w3 = off_w[(k + 3) * 72 + c];
        } else if (c < 108) {
            int cm = c - 72;
            w0 = mask_w[(k + 0) * 36 + cm]; w1 = mask_w[(k + 1) * 36 + cm];
            w2 = mask_w[(k + 2) * 36 + cm]; w3 = mask_w[(k + 3) * 36 + cm];
        }
        #pragma unroll
        for (int p = 0; p < 16; p++) {
            float4 xv = *(const float4*)&xs[(pbase + p) * CH + k];
            acc[p] += xv.x * w0 + xv.y * w1 + xv.z * w2 + xv.w * w3;
        }
    }
    if (act) {
        #pragma unroll
        for (int p = 0; p < 16; p++) {
            int pix = pix0 + pbase + p;
            om[(size_t)pix * 108 + c] = acc[p];
        }
    }
}

// ---------------- K5: softmax + bilinear deformable sampling -> core --------
__global__ __launch_bounds__(256) void k5_core(const float* __restrict__ xpad,
                                               const float* __restrict__ om,
                                               float* __restrict__ core) {
    __shared__ float oms[2][108];
    __shared__ float sm[2][36];
    int t = threadIdx.x;
    int pl = t >> 7, tt = t & 127, g = tt >> 5, c = tt & 31;
    for (int q = t; q < 216; q += 256) {
        int pp = q / 108, idx = q % 108;
        oms[pp][idx] = om[(size_t)(blockIdx.x * 2 + pp) * 108 + idx];
    }
    __syncthreads();
    if (c == 0) {
        const float* lg = &oms[pl][72 + g * 9];
        float mx = lg[0];
        #pragma unroll
        for (int i = 1; i < 9; i++) mx = fmaxf(mx, lg[i]);
        float e[9], sum = 0.f;
        #pragma unroll
        for (int i = 0; i < 9; i++) { e[i] = expf(lg[i] - mx); sum += e[i]; }
        float inv = 1.f / sum;
        #pragma unroll
        for (int i = 0; i < 9; i++) sm[pl][g * 9 + i] = e[i] * inv;
    }
    __syncthreads();
    int pix = blockIdx.x * 2 + pl;
    int w = pix & 63, h = (pix >> 6) & 63, b = pix >> 12;
    const float* xb = xpad + (size_t)b * HP * WP * CH + g * GCH + c;
    float acc = 0.f;
    #pragma unroll
    for (int p = 0; p < 9; p++) {
        float offx = oms[pl][(g * 9 + p) * 2];
        float offy = oms[pl][(g * 9 + p) * 2 + 1];
        float m = sm[pl][g * 9 + p];
        float ix = (float)(w + (p / 3)) + offx;   // = w + 1 + (p/3 - 1) + offx
        float iy = (float)(h + (p % 3)) + offy;
        float x0f = floorf(ix), y0f = floorf(iy);
        float fx = ix - x0f, fy = iy - y0f;
        int x0 = (int)x0f, y0 = (int)y0f;
        float v00, v10, v01, v11;
        {
            int xi = x0, yi = y0;
            bool vv = ((unsigned)xi < (unsigned)WP) && ((unsigned)yi < (unsigned)HP);
            int xc = min(max(xi, 0), WP - 1), yc = min(max(yi, 0), HP - 1);
            float val = xb[(size_t)(yc * WP + xc) * CH];
            v00 = vv ? val : 0.f;
        }
        {
            int xi = x0 + 1, yi = y0;
            bool vv = ((unsigned)xi < (unsigned)WP) && ((unsigned)yi < (unsigned)HP);
            int xc = min(max(xi, 0), WP - 1), yc = min(max(yi, 0), HP - 1);
            float val = xb[(size_t)(yc * WP + xc) * CH];
            v10 = vv ? val : 0.f;
        }
        {
            int xi = x0, yi = y0 + 1;
            bool vv = ((unsigned)xi < (unsigned)WP) && ((unsigned)yi < (unsigned)HP);
            int xc = min(max(xi, 0), WP - 1), yc = min(max(yi, 0), HP - 1);
            float val = xb[(size_t)(yc * WP + xc) * CH];
            v01 = vv ? val : 0.f;
        }
        {
            int xi = x0 + 1, yi = y0 + 1;
            bool vv = ((unsigned)xi < (unsigned)WP) && ((unsigned)yi < (unsigned)HP);
            int xc = min(max(xi, 0), WP - 1), yc = min(max(yi, 0), HP - 1);
            float val = xb[(size_t)(yc * WP + xc) * CH];
            v11 = vv ? val : 0.f;
        }
        acc += m * (v00 * (1.f - fx) * (1.f - fy) + v10 * fx * (1.f - fy)
                  + v01 * (1.f - fx) * fy         + v11 * fx * fy);
    }
    core[(size_t)pix * CH + tt] = acc;
}

// ---------------- K6: out_proj GEMM + NHWC->NCHW store ----------------------
__global__ __launch_bounds__(256) void k6_outproj(const float* __restrict__ core,
                                                  const float* __restrict__ Wm,
                                                  const float* __restrict__ bias,
                                                  float* __restrict__ out) {
    __shared__ float xs[32 * CH];
    __shared__ float res[32 * 129];
    int pix0 = blockIdx.x * 32;
    int t = threadIdx.x;
    const float4* src = (const float4*)(core + (size_t)pix0 * CH);
    float4* xs4 = (float4*)xs;
    for (int q = t; q < 1024; q += 256) xs4[q] = src[q];
    __syncthreads();
    int c = t & 127, half = t >> 7;
    int pbase = half * 16;
    float acc[16];
    float bv = bias[c];
    #pragma unroll
    for (int p = 0; p < 16; p++) acc[p] = bv;
    for (int k = 0; k < CH; k += 4) {
        float w0 = Wm[(k + 0) * CH + c];
        float w1 = Wm[(k + 1) * CH + c];
        float w2 = Wm[(k + 2) * CH + c];
        float w3 = Wm[(k + 3) * CH + c];
        #pragma unroll
        for (int p = 0; p < 16; p++) {
            float4 xv = *(const float4*)&xs[(pbase + p) * CH + k];
            acc[p] += xv.x * w0 + xv.y * w1 + xv.z * w2 + xv.w * w3;
        }
    }
    #pragma unroll
    for (int p = 0; p < 16; p++) res[(pbase + p) * 129 + c] = acc[p];
    __syncthreads();
    int b = pix0 >> 12, h = (pix0 >> 6) & 63, w0i = pix0 & 63;
    for (int q = t; q < 4096; q += 256) {
        int cc = q >> 5, ww = q & 31;
        out[(size_t)((b * CH + cc) * HH + h) * WWID + (w0i + ww)] = res[ww * 129 + cc];
    }
}

extern "C" void kernel_launch(void* const* d_in, const int* in_sizes, int n_in,
                              void* d_out, int out_size, void* d_ws, size_t ws_size,
                              hipStream_t stream) {
    const float* x        = (const float*)d_in[0];
    const float* conv_w   = (const float*)d_in[1];
    const float* conv_b   = (const float*)d_in[2];
    const float* in_proj_w= (const float*)d_in[3];
    const float* in_proj_b= (const float*)d_in[4];
    const float* dw_w     = (const float*)d_in[5];
    const float* dw_b     = (const float*)d_in[6];
    const float* ln_g     = (const float*)d_in[7];
    const float* ln_b     = (const float*)d_in[8];
    const float* off_w    = (const float*)d_in[9];
    const float* off_b    = (const float*)d_in[10];
    const float* mask_w   = (const float*)d_in[11];
    const float* mask_b   = (const float*)d_in[12];
    const float* out_proj_w = (const float*)d_in[13];
    const float* out_proj_b = (const float*)d_in[14];
    float* out = (float*)d_out;

    float* ws = (float*)d_ws;
    // workspace layout (floats); om aliases xt, core aliases y (lifetimes disjoint)
    const size_t O_XT   = 0;                      // B*3844*128 = 3,936,512 (also om: 32768*108)
    const size_t O_W1T  = 3936512;                // 16,384
    const size_t O_Y    = O_W1T + 16384;          // 4,194,304 (also core)
    const size_t O_XPAD = O_Y + 4194304;          // 8*66*66*128 = 4,460,544
    const size_t O_D    = O_XPAD + 4460544;       // 4,194,304
    float* xt   = ws + O_XT;
    float* om   = ws + O_XT;      // alias: xt dead after K1
    float* w1t  = ws + O_W1T;
    float* y    = ws + O_Y;
    float* core = ws + O_Y;       // alias: y dead after K3
    float* xpad = ws + O_XPAD;
    float* dbuf = ws + O_D;

    t0_wtrans<<<64, 256, 0, stream>>>(conv_w, w1t);
    t1_xtrans<<<dim3(121, 4, 8), 256, 0, stream>>>(x, xt);
    hipMemsetAsync(xpad, 0, (size_t)8 * HP * WP * CH * sizeof(float), stream);
    k1_conv1x1<<<NPIX / 32, 256, 0, stream>>>(xt, w1t, conv_b, y);
    k2_inproj<<<NPIX / 32, 256, 0, stream>>>(y, in_proj_w, in_proj_b, xpad);
    k3_dwln<<<NPIX / 2, 256, 0, stream>>>(y, dw_w, dw_b, ln_g, ln_b, dbuf);
    k4_offmask<<<NPIX / 32, 256, 0, stream>>>(dbuf, off_w, off_b, mask_w, mask_b, om);
    k5_core<<<NPIX / 2, 256, 0, stream>>>(xpad, om, core);
    k6_outproj<<<NPIX / 32, 256, 0, stream>>>(core, out_proj_w, out_proj_b, out);
}

// Round 3
// 271.068 us; speedup vs baseline: 1.1858x; 1.1858x over previous
//
#include <hip/hip_runtime.h>
#include <math.h>

#define BB 8
#define CH 128
#define HH 64
#define WWID 64
#define HIN 62
#define WIN 62
#define SPIN (HIN*WIN)      // 3844
#define HP 66
#define WP 66
#define GG 4
#define GCH 32
#define NPIX (BB*HH*WWID)   // 32768

// ---------------- T0: transpose conv_w [Cout][Cin] -> w1t[k][cout] ----------
__global__ __launch_bounds__(256) void t0_wtrans(const float* __restrict__ conv_w,
                                                 float* __restrict__ w1t) {
    int idx = blockIdx.x * 256 + threadIdx.x;      // 0..16383
    int cout = idx >> 7, k = idx & 127;
    w1t[k * CH + cout] = conv_w[cout * CH + k];
}

// ---------------- T1: transpose x NCHW [B][128][3844] -> xt [B][3844][128] --
__global__ __launch_bounds__(256) void t1_xtrans(const float* __restrict__ x,
                                                 float* __restrict__ xt) {
    __shared__ float tile[32][33];
    int b = blockIdx.z;
    int c0 = blockIdx.y * 32;
    int s0 = blockIdx.x * 32;
    int tx = threadIdx.x & 31, ty = threadIdx.x >> 5;   // 32 x 8
    const float* xb = x + (size_t)b * CH * SPIN;
    #pragma unroll
    for (int i = 0; i < 32; i += 8) {
        int c = c0 + ty + i, s = s0 + tx;
        tile[ty + i][tx] = (s < SPIN) ? xb[(size_t)c * SPIN + s] : 0.f;
    }
    __syncthreads();
    float* xtb = xt + (size_t)b * SPIN * CH;
    #pragma unroll
    for (int i = 0; i < 32; i += 8) {
        int s = s0 + ty + i, c = c0 + tx;
        if (s < SPIN) xtb[(size_t)s * CH + c] = tile[tx][ty + i];
    }
}

// ================= GEMM tiling: 64 px/block, 256 thr, 8px x 4ch per thread ==
// lane = t&31 -> channel group c = lane*4 ; prow = t>>5 -> pixels prow*8..+7

// ---------------- K1: 1x1 conv (pad=1) -> y NHWC [B][64][64][128] -----------
__global__ __launch_bounds__(256) void k1_conv1x1(const float* __restrict__ xt,
                                                  const float* __restrict__ w1t,
                                                  const float* __restrict__ conv_b,
                                                  float* __restrict__ y) {
    __shared__ float xs[64 * CH];                   // 32 KB
    int pix0 = blockIdx.x * 64;
    int t = threadIdx.x;
    float4* xs4 = (float4*)xs;
    // block covers one row: b,h fixed; w = 0..63
    int h = (pix0 >> 6) & 63, b = pix0 >> 12;
    bool hin = (h >= 1 && h <= 62);
    for (int q = t; q < 2048; q += 256) {
        int p = q >> 5, c4 = q & 31;                // p = w
        float4 v = make_float4(0.f, 0.f, 0.f, 0.f);
        if (hin && p >= 1 && p <= 62) {
            const float4* src = (const float4*)(xt + (size_t)((b * HIN + (h - 1)) * WIN + (p - 1)) * CH);
            v = src[c4];
        }
        xs4[q] = v;
    }
    __syncthreads();
    int lane = t & 31, prow = t >> 5;
    int c = lane * 4, p0 = prow * 8;
    float4 acc[8];
    float4 bv = *(const float4*)&conv_b[c];
    #pragma unroll
    for (int i = 0; i < 8; i++) acc[i] = bv;
    for (int k = 0; k < CH; k += 4) {
        float4 w0 = *(const float4*)&w1t[(k + 0) * CH + c];
        float4 w1 = *(const float4*)&w1t[(k + 1) * CH + c];
        float4 w2 = *(const float4*)&w1t[(k + 2) * CH + c];
        float4 w3 = *(const float4*)&w1t[(k + 3) * CH + c];
        #pragma unroll
        for (int i = 0; i < 8; i++) {
            float4 xv = *(const float4*)&xs[(p0 + i) * CH + k];
            acc[i].x += xv.x * w0.x + xv.y * w1.x + xv.z * w2.x + xv.w * w3.x;
            acc[i].y += xv.x * w0.y + xv.y * w1.y + xv.z * w2.y + xv.w * w3.y;
            acc[i].z += xv.x * w0.z + xv.y * w1.z + xv.z * w2.z + xv.w * w3.z;
            acc[i].w += xv.x * w0.w + xv.y * w1.w + xv.z * w2.w + xv.w * w3.w;
        }
    }
    #pragma unroll
    for (int i = 0; i < 8; i++) {
        *(float4*)&y[(size_t)(pix0 + p0 + i) * CH + c] = acc[i];
    }
}

// ---------------- K2: in_proj -> xpad interior [B][66][66][128] -------------
__global__ __launch_bounds__(256) void k2_inproj(const float* __restrict__ y,
                                                 const float* __restrict__ Wm,
                                                 const float* __restrict__ bias,
                                                 float* __restrict__ xpad) {
    __shared__ float xs[64 * CH];
    int pix0 = blockIdx.x * 64;
    int t = threadIdx.x;
    const float4* src = (const float4*)(y + (size_t)pix0 * CH);
    float4* xs4 = (float4*)xs;
    for (int q = t; q < 2048; q += 256) xs4[q] = src[q];
    __syncthreads();
    int lane = t & 31, prow = t >> 5;
    int c = lane * 4, p0 = prow * 8;
    float4 acc[8];
    float4 bv = *(const float4*)&bias[c];
    #pragma unroll
    for (int i = 0; i < 8; i++) acc[i] = bv;
    for (int k = 0; k < CH; k += 4) {
        float4 w0 = *(const float4*)&Wm[(k + 0) * CH + c];
        float4 w1 = *(const float4*)&Wm[(k + 1) * CH + c];
        float4 w2 = *(const float4*)&Wm[(k + 2) * CH + c];
        float4 w3 = *(const float4*)&Wm[(k + 3) * CH + c];
        #pragma unroll
        for (int i = 0; i < 8; i++) {
            float4 xv = *(const float4*)&xs[(p0 + i) * CH + k];
            acc[i].x += xv.x * w0.x + xv.y * w1.x + xv.z * w2.x + xv.w * w3.x;
            acc[i].y += xv.x * w0.y + xv.y * w1.y + xv.z * w2.y + xv.w * w3.y;
            acc[i].z += xv.x * w0.z + xv.y * w1.z + xv.z * w2.z + xv.w * w3.z;
            acc[i].w += xv.x * w0.w + xv.y * w1.w + xv.z * w2.w + xv.w * w3.w;
        }
    }
    int h = (pix0 >> 6) & 63, b = pix0 >> 12;
    #pragma unroll
    for (int i = 0; i < 8; i++) {
        int w = p0 + i;                              // block = one row
        *(float4*)&xpad[(size_t)(((b * HP) + h + 1) * WP + (w + 1)) * CH + c] = acc[i];
    }
}

// ---------------- K3: depthwise 3x3 + LayerNorm + GELU -> d -----------------
__global__ __launch_bounds__(256) void k3_dwln(const float* __restrict__ y,
                                               const float* __restrict__ dw_w,
                                               const float* __restrict__ dw_b,
                                               const float* __restrict__ ln_g,
                                               const float* __restrict__ ln_b,
                                               float* __restrict__ d) {
    int t = threadIdx.x;
    int pl = t >> 7;
    int pix = blockIdx.x * 2 + pl;
    int c = t & 127;
    int w = pix & 63, h = (pix >> 6) & 63, b = pix >> 12;
    float acc = dw_b[c];
    #pragma unroll
    for (int ky = 0; ky < 3; ky++) {
        int hh = h + ky - 1;
        if (hh < 0 || hh > 63) continue;
        #pragma unroll
        for (int kx = 0; kx < 3; kx++) {
            int ww = w + kx - 1;
            if (ww < 0 || ww > 63) continue;
            acc += y[(size_t)((b * HH + hh) * WWID + ww) * CH + c] * dw_w[c * 9 + ky * 3 + kx];
        }
    }
    float s = acc, ss = acc * acc;
    #pragma unroll
    for (int off = 1; off < 64; off <<= 1) {
        s  += __shfl_xor(s, off);
        ss += __shfl_xor(ss, off);
    }
    __shared__ float red[8];
    int wave = t >> 6;
    if ((t & 63) == 0) { red[wave * 2] = s; red[wave * 2 + 1] = ss; }
    __syncthreads();
    float S  = red[pl * 4 + 0] + red[pl * 4 + 2];
    float SS = red[pl * 4 + 1] + red[pl * 4 + 3];
    float mu = S * (1.f / 128.f);
    float var = SS * (1.f / 128.f) - mu * mu;
    float xln = (acc - mu) * rsqrtf(var + 1e-5f) * ln_g[c] + ln_b[c];
    float gel = 0.5f * xln * (1.f + erff(xln * 0.70710678118654752f));
    d[(size_t)pix * CH + c] = gel;
}

// ---------------- K4: offset(72) + mask-logits(36) GEMM -> om [pix][108] ----
__global__ __launch_bounds__(256) void k4_offmask(const float* __restrict__ din,
                                                  const float* __restrict__ off_w,
                                                  const float* __restrict__ off_b,
                                                  const float* __restrict__ mask_w,
                                                  const float* __restrict__ mask_b,
                                                  float* __restrict__ om) {
    __shared__ float xs[64 * CH];
    int pix0 = blockIdx.x * 64;
    int t = threadIdx.x;
    const float4* src = (const float4*)(din + (size_t)pix0 * CH);
    float4* xs4 = (float4*)xs;
    for (int q = t; q < 2048; q += 256) xs4[q] = src[q];
    __syncthreads();
    int lane = t & 31, prow = t >> 5;
    int c = lane * 4, p0 = prow * 8;
    // lanes 0..17 -> off_w (c 0..71, stride 72); 18..26 -> mask_w (cm 0..35, stride 36)
    const float* wbase; int wstride, cc;
    float4 bv = make_float4(0.f, 0.f, 0.f, 0.f);
    if (lane < 18)      { wbase = off_w;  wstride = 72; cc = c;      bv = *(const float4*)&off_b[c]; }
    else if (lane < 27) { wbase = mask_w; wstride = 36; cc = c - 72; bv = *(const float4*)&mask_b[c - 72]; }
    else                { wbase = mask_w; wstride = 36; cc = 0; }
    float4 acc[8];
    #pragma unroll
    for (int i = 0; i < 8; i++) acc[i] = bv;
    for (int k = 0; k < CH; k += 4) {
        float4 w0 = *(const float4*)&wbase[(k + 0) * wstride + cc];
        float4 w1 = *(const float4*)&wbase[(k + 1) * wstride + cc];
        float4 w2 = *(const float4*)&wbase[(k + 2) * wstride + cc];
        float4 w3 = *(const float4*)&wbase[(k + 3) * wstride + cc];
        #pragma unroll
        for (int i = 0; i < 8; i++) {
            float4 xv = *(const float4*)&xs[(p0 + i) * CH + k];
            acc[i].x += xv.x * w0.x + xv.y * w1.x + xv.z * w2.x + xv.w * w3.x;
            acc[i].y += xv.x * w0.y + xv.y * w1.y + xv.z * w2.y + xv.w * w3.y;
            acc[i].z += xv.x * w0.z + xv.y * w1.z + xv.z * w2.z + xv.w * w3.z;
            acc[i].w += xv.x * w0.w + xv.y * w1.w + xv.z * w2.w + xv.w * w3.w;
        }
    }
    if (lane < 27) {
        #pragma unroll
        for (int i = 0; i < 8; i++) {
            *(float4*)&om[(size_t)(pix0 + p0 + i) * 108 + c] = acc[i];
        }
    }
}

// ---------------- K5: softmax + precomputed-tap bilinear sampling -> core ---
__global__ __launch_bounds__(256) void k5_core(const float* __restrict__ xpad,
                                               const float* __restrict__ om,
                                               float* __restrict__ core) {
    __shared__ float oms[2][108];
    __shared__ float sm[2][36];
    __shared__ int4   smo[2][36];   // 4 corner linear offsets (floats)
    __shared__ float4 smw[2][36];   // 4 corner weights (mask folded, invalid->0)
    int t = threadIdx.x;
    int pix0 = blockIdx.x * 2;
    for (int q = t; q < 216; q += 256) {
        int pp = q / 108, idx = q % 108;
        oms[pp][idx] = om[(size_t)(pix0 + pp) * 108 + idx];
    }
    __syncthreads();
    if (t < 8) {                                   // softmax per (pl,g)
        int pl = t >> 2, g = t & 3;
        const float* lg = &oms[pl][72 + g * 9];
        float mx = lg[0];
        #pragma unroll
        for (int i = 1; i < 9; i++) mx = fmaxf(mx, lg[i]);
        float e[9], sum = 0.f;
        #pragma unroll
        for (int i = 0; i < 9; i++) { e[i] = expf(lg[i] - mx); sum += e[i]; }
        float inv = 1.f / sum;
        #pragma unroll
        for (int i = 0; i < 9; i++) sm[pl][g * 9 + i] = e[i] * inv;
    }
    __syncthreads();
    if (t < 72) {                                  // per-tap precompute
        int pl = t / 36, gp = t % 36;
        int p = gp % 9;
        int pix = pix0 + pl;
        int w = pix & 63, h = (pix >> 6) & 63;
        float offx = oms[pl][gp * 2];
        float offy = oms[pl][gp * 2 + 1];
        float m = sm[pl][gp];
        float ix = (float)(w + (p / 3)) + offx;
        float iy = (float)(h + (p % 3)) + offy;
        float x0f = floorf(ix), y0f = floorf(iy);
        float fx = ix - x0f, fy = iy - y0f;
        int x0 = (int)x0f, y0 = (int)y0f;
        int xi[4] = { x0, x0 + 1, x0,     x0 + 1 };
        int yi[4] = { y0, y0,     y0 + 1, y0 + 1 };
        float wt[4] = { m * (1.f - fx) * (1.f - fy), m * fx * (1.f - fy),
                        m * (1.f - fx) * fy,         m * fx * fy };
        int   lo[4];
        #pragma unroll
        for (int cnr = 0; cnr < 4; cnr++) {
            bool vv = ((unsigned)xi[cnr] < (unsigned)WP) && ((unsigned)yi[cnr] < (unsigned)HP);
            int xc = min(max(xi[cnr], 0), WP - 1), yc = min(max(yi[cnr], 0), HP - 1);
            lo[cnr] = (yc * WP + xc) * CH;
            if (!vv) wt[cnr] = 0.f;
        }
        smo[pl][gp] = make_int4(lo[0], lo[1], lo[2], lo[3]);
        smw[pl][gp] = make_float4(wt[0], wt[1], wt[2], wt[3]);
    }
    __syncthreads();
    int pl = t >> 7, tt = t & 127, g = tt >> 5, cl = tt & 31;
    int pix = pix0 + pl;
    int b = pix >> 12;
    const float* base = xpad + (size_t)b * HP * WP * CH + g * GCH + cl;
    float acc = 0.f;
    #pragma unroll
    for (int p = 0; p < 9; p++) {
        int4   o  = smo[pl][g * 9 + p];
        float4 wv = smw[pl][g * 9 + p];
        acc += wv.x * base[o.x] + wv.y * base[o.y] + wv.z * base[o.z] + wv.w * base[o.w];
    }
    core[(size_t)pix * CH + tt] = acc;
}

// ---------------- K6: out_proj GEMM + NHWC->NCHW store ----------------------
__global__ __launch_bounds__(256) void k6_outproj(const float* __restrict__ core,
                                                  const float* __restrict__ Wm,
                                                  const float* __restrict__ bias,
                                                  float* __restrict__ out) {
    __shared__ float smem[64 * 129];               // xs view (64*128) then res view (stride 129)
    int pix0 = blockIdx.x * 64;
    int t = threadIdx.x;
    const float4* src = (const float4*)(core + (size_t)pix0 * CH);
    float4* xs4 = (float4*)smem;
    for (int q = t; q < 2048; q += 256) xs4[q] = src[q];
    __syncthreads();
    int lane = t & 31, prow = t >> 5;
    int c = lane * 4, p0 = prow * 8;
    float4 acc[8];
    float4 bv = *(const float4*)&bias[c];
    #pragma unroll
    for (int i = 0; i < 8; i++) acc[i] = bv;
    for (int k = 0; k < CH; k += 4) {
        float4 w0 = *(const float4*)&Wm[(k + 0) * CH + c];
        float4 w1 = *(const float4*)&Wm[(k + 1) * CH + c];
        float4 w2 = *(const float4*)&Wm[(k + 2) * CH + c];
        float4 w3 = *(const float4*)&Wm[(k + 3) * CH + c];
        #pragma unroll
        for (int i = 0; i < 8; i++) {
            float4 xv = *(const float4*)&smem[(p0 + i) * CH + k];
            acc[i].x += xv.x * w0.x + xv.y * w1.x + xv.z * w2.x + xv.w * w3.x;
            acc[i].y += xv.x * w0.y + xv.y * w1.y + xv.z * w2.y + xv.w * w3.y;
            acc[i].z += xv.x * w0.z + xv.y * w1.z + xv.z * w2.z + xv.w * w3.z;
            acc[i].w += xv.x * w0.w + xv.y * w1.w + xv.z * w2.w + xv.w * w3.w;
        }
    }
    __syncthreads();                               // all xs reads done; reuse smem as res
    #pragma unroll
    for (int i = 0; i < 8; i++) {
        int row = (p0 + i) * 129 + c;
        smem[row + 0] = acc[i].x;
        smem[row + 1] = acc[i].y;
        smem[row + 2] = acc[i].z;
        smem[row + 3] = acc[i].w;
    }
    __syncthreads();
    int b = pix0 >> 12, h = (pix0 >> 6) & 63;
    for (int q = t; q < 8192; q += 256) {
        int cc = q >> 6, ww = q & 63;
        out[(size_t)((b * CH + cc) * HH + h) * WWID + ww] = smem[ww * 129 + cc];
    }
}

extern "C" void kernel_launch(void* const* d_in, const int* in_sizes, int n_in,
                              void* d_out, int out_size, void* d_ws, size_t ws_size,
                              hipStream_t stream) {
    const float* x        = (const float*)d_in[0];
    const float* conv_w   = (const float*)d_in[1];
    const float* conv_b   = (const float*)d_in[2];
    const float* in_proj_w= (const float*)d_in[3];
    const float* in_proj_b= (const float*)d_in[4];
    const float* dw_w     = (const float*)d_in[5];
    const float* dw_b     = (const float*)d_in[6];
    const float* ln_g     = (const float*)d_in[7];
    const float* ln_b     = (const float*)d_in[8];
    const float* off_w    = (const float*)d_in[9];
    const float* off_b    = (const float*)d_in[10];
    const float* mask_w   = (const float*)d_in[11];
    const float* mask_b   = (const float*)d_in[12];
    const float* out_proj_w = (const float*)d_in[13];
    const float* out_proj_b = (const float*)d_in[14];
    float* out = (float*)d_out;

    float* ws = (float*)d_ws;
    const size_t O_XT   = 0;                      // B*3844*128 = 3,936,512 (also om: 32768*108)
    const size_t O_W1T  = 3936512;                // 16,384
    const size_t O_Y    = O_W1T + 16384;          // 4,194,304 (also core)
    const size_t O_XPAD = O_Y + 4194304;          // 8*66*66*128 = 4,460,544
    const size_t O_D    = O_XPAD + 4460544;       // 4,194,304
    float* xt   = ws + O_XT;
    float* om   = ws + O_XT;      // alias: xt dead after K1
    float* w1t  = ws + O_W1T;
    float* y    = ws + O_Y;
    float* core = ws + O_Y;       // alias: y dead after K3
    float* xpad = ws + O_XPAD;
    float* dbuf = ws + O_D;

    t0_wtrans<<<64, 256, 0, stream>>>(conv_w, w1t);
    t1_xtrans<<<dim3(121, 4, 8), 256, 0, stream>>>(x, xt);
    hipMemsetAsync(xpad, 0, (size_t)8 * HP * WP * CH * sizeof(float), stream);
    k1_conv1x1<<<NPIX / 64, 256, 0, stream>>>(xt, w1t, conv_b, y);
    k2_inproj<<<NPIX / 64, 256, 0, stream>>>(y, in_proj_w, in_proj_b, xpad);
    k3_dwln<<<NPIX / 2, 256, 0, stream>>>(y, dw_w, dw_b, ln_g, ln_b, dbuf);
    k4_offmask<<<NPIX / 64, 256, 0, stream>>>(dbuf, off_w, off_b, mask_w, mask_b, om);
    k5_core<<<NPIX / 2, 256, 0, stream>>>(xpad, om, core);
    k6_outproj<<<NPIX / 64, 256, 0, stream>>>(core, out_proj_w, out_proj_b, out);
}